// Round 3
// baseline (157.903 us; speedup 1.0000x reference)
//
#include <hip/hip_runtime.h>

#define NC 320   // coalition size
#define DIM 512

// ---------------------------------------------------------------------------
// q = x @ Wq^T + bq ; k = x @ Wk^T + bk, split-K x8 with fp32 atomicAdd.
// grid (8, 5, 16): x = col tile (64), y = row tile (64), z: mat=z>>3, split=z&7.
// 64x64 tile, BK=32, 4x4 micro-tile. Both operands staged k-major [32][68]:
// fragment reads are b128 (A: 4-addr broadcast, B: 2-way = free). Staging
// stores are scalar with a 4-way conflict (unavoidable with 16B-aligned pad;
// ~1.58x on ~20% of LDS ops — accepted). Bias added by split 0 only.
// ---------------------------------------------------------------------------
__global__ __launch_bounds__(256) void gemm_qk3(
    const float* __restrict__ x,
    const float* __restrict__ Wq, const float* __restrict__ bq,
    const float* __restrict__ Wk, const float* __restrict__ bk,
    float* __restrict__ qout, float* __restrict__ kout)
{
  const int z = blockIdx.z;
  const float* __restrict__ W    = (z & 8) ? Wk : Wq;
  const float* __restrict__ bias = (z & 8) ? bk : bq;
  float* __restrict__ out        = (z & 8) ? kout : qout;
  const int kb = (z & 7) * 64;      // this split's K chunk [kb, kb+64)
  const int i0 = blockIdx.y * 64;
  const int c0 = blockIdx.x * 64;

  __shared__ __align__(16) float As[32][68];   // [kk][row]
  __shared__ __align__(16) float Bs[32][68];   // [kk][col]

  const int t  = threadIdx.x;
  const int sr = t >> 2;            // staged row/col 0..63
  const int kc = (t & 3) << 3;      // staged k offset 0,8,16,24
  const int ty = t >> 4;            // 0..15 row quad
  const int tx = t & 15;            // 0..15 col quad

  float acc[4][4] = {};

  const float* xp = x + (i0 + sr) * DIM + kc;
  const float* wp = W + (c0 + sr) * DIM + kc;

  for (int k0 = kb; k0 < kb + 64; k0 += 32) {
    const float4 xa = *(const float4*)(xp + k0);
    const float4 xb = *(const float4*)(xp + k0 + 4);
    const float4 wa = *(const float4*)(wp + k0);
    const float4 wb = *(const float4*)(wp + k0 + 4);
    __syncthreads();
    As[kc+0][sr]=xa.x; As[kc+1][sr]=xa.y; As[kc+2][sr]=xa.z; As[kc+3][sr]=xa.w;
    As[kc+4][sr]=xb.x; As[kc+5][sr]=xb.y; As[kc+6][sr]=xb.z; As[kc+7][sr]=xb.w;
    Bs[kc+0][sr]=wa.x; Bs[kc+1][sr]=wa.y; Bs[kc+2][sr]=wa.z; Bs[kc+3][sr]=wa.w;
    Bs[kc+4][sr]=wb.x; Bs[kc+5][sr]=wb.y; Bs[kc+6][sr]=wb.z; Bs[kc+7][sr]=wb.w;
    __syncthreads();
    #pragma unroll
    for (int kk = 0; kk < 32; ++kk) {
      const float4 a4 = *(const float4*)&As[kk][ty * 4];
      const float4 b4 = *(const float4*)&Bs[kk][tx * 4];
      const float a[4] = {a4.x, a4.y, a4.z, a4.w};
      const float b[4] = {b4.x, b4.y, b4.z, b4.w};
      #pragma unroll
      for (int i = 0; i < 4; ++i)
        #pragma unroll
        for (int j = 0; j < 4; ++j)
          acc[i][j] = fmaf(a[i], b[j], acc[i][j]);
    }
  }

  const bool addb = (z & 7) == 0;
  const float4 bv4 = *(const float4*)&bias[c0 + tx * 4];
  const float bb[4] = {addb ? bv4.x : 0.f, addb ? bv4.y : 0.f,
                       addb ? bv4.z : 0.f, addb ? bv4.w : 0.f};
  #pragma unroll
  for (int i = 0; i < 4; ++i)
    #pragma unroll
    for (int j = 0; j < 4; ++j)
      atomicAdd(&out[(i0 + ty*4 + i) * DIM + c0 + tx*4 + j], acc[i][j] + bb[j]);
}

// ---------------------------------------------------------------------------
// S[i][j] += scale * sum_{k in chunk} q[i,k]*k[j,k], split-K x16.
// grid (5, 5, 16): x = j tile, y = i tile, z = split (chunk 32 = one BK).
// Same 64x64 / 4x4 micro structure as gemm_qk3.
// ---------------------------------------------------------------------------
__global__ __launch_bounds__(256) void scores2(
    const float* __restrict__ q, const float* __restrict__ k,
    float* __restrict__ S)
{
  const int kb = blockIdx.z * 32;
  const int i0 = blockIdx.y * 64;
  const int j0 = blockIdx.x * 64;

  __shared__ __align__(16) float As[32][68];
  __shared__ __align__(16) float Bs[32][68];

  const int t  = threadIdx.x;
  const int sr = t >> 2;
  const int kc = (t & 3) << 3;
  const int ty = t >> 4;
  const int tx = t & 15;

  const float4 qa = *(const float4*)(q + (i0 + sr) * DIM + kb + kc);
  const float4 qb = *(const float4*)(q + (i0 + sr) * DIM + kb + kc + 4);
  const float4 ka = *(const float4*)(k + (j0 + sr) * DIM + kb + kc);
  const float4 kbv= *(const float4*)(k + (j0 + sr) * DIM + kb + kc + 4);
  As[kc+0][sr]=qa.x; As[kc+1][sr]=qa.y; As[kc+2][sr]=qa.z; As[kc+3][sr]=qa.w;
  As[kc+4][sr]=qb.x; As[kc+5][sr]=qb.y; As[kc+6][sr]=qb.z; As[kc+7][sr]=qb.w;
  Bs[kc+0][sr]=ka.x; Bs[kc+1][sr]=ka.y; Bs[kc+2][sr]=ka.z; Bs[kc+3][sr]=ka.w;
  Bs[kc+4][sr]=kbv.x;Bs[kc+5][sr]=kbv.y;Bs[kc+6][sr]=kbv.z;Bs[kc+7][sr]=kbv.w;
  __syncthreads();

  float acc[4][4] = {};
  #pragma unroll
  for (int kk = 0; kk < 32; ++kk) {
    const float4 a4 = *(const float4*)&As[kk][ty * 4];
    const float4 b4 = *(const float4*)&Bs[kk][tx * 4];
    const float a[4] = {a4.x, a4.y, a4.z, a4.w};
    const float b[4] = {b4.x, b4.y, b4.z, b4.w};
    #pragma unroll
    for (int i = 0; i < 4; ++i)
      #pragma unroll
      for (int j = 0; j < 4; ++j)
        acc[i][j] = fmaf(a[i], b[j], acc[i][j]);
  }

  const float scale = 0.044194173824159216f;  // 1/sqrt(512)
  #pragma unroll
  for (int i = 0; i < 4; ++i)
    #pragma unroll
    for (int j = 0; j < 4; ++j)
      atomicAdd(&S[(i0 + ty*4 + i) * NC + j0 + tx*4 + j], acc[i][j] * scale);
}

// ---------------------------------------------------------------------------
// h[e] = sum_d Wv[d,e] * wA[d]   (wA = Wc[0, 0:512])
// ---------------------------------------------------------------------------
__global__ __launch_bounds__(256) void compute_h(
    const float* __restrict__ Wv, const float* __restrict__ Wc,
    float* __restrict__ h)
{
  const int e  = blockIdx.x * 256 + threadIdx.x;  // 0..511
  const int d0 = blockIdx.y * 32;
  float s = 0.f;
  #pragma unroll
  for (int d = 0; d < 32; ++d)
    s = fmaf(Wv[(d0 + d) * DIM + e], Wc[d0 + d], s);
  atomicAdd(&h[e], s);
}

// ---------------------------------------------------------------------------
// One block per query row i, e[] read from precomputed S:
//   e = exp(S[i,:] - rowmax); prefix sums -> W[j]=1/(j*S[j]) for j>i;
//   Csuf[m] = sum_{j>=m} W[j];  P[kk] += e[kk]*Csuf[max(i,kk)+1]
// ---------------------------------------------------------------------------
__global__ __launch_bounds__(256) void row_ops(
    const float* __restrict__ S, float* __restrict__ P)
{
  const int i    = blockIdx.x;
  const int t    = threadIdx.x;
  const int lane = t & 63;
  const int wave = t >> 6;

  __shared__ float e[NC];
  __shared__ float Warr[NC];
  __shared__ float Csuf[NC + 1];
  __shared__ float wred[4];

  for (int kk = t; kk < NC; kk += 256) e[kk] = S[i * NC + kk];
  __syncthreads();

  float m = -1e30f;
  for (int kk = t; kk < NC; kk += 256) m = fmaxf(m, e[kk]);
  #pragma unroll
  for (int off = 32; off; off >>= 1) m = fmaxf(m, __shfl_down(m, off));
  if (lane == 0) wred[wave] = m;
  __syncthreads();
  m = fmaxf(fmaxf(wred[0], wred[1]), fmaxf(wred[2], wred[3]));

  for (int kk = t; kk < NC; kk += 256) e[kk] = __expf(e[kk] - m);
  __syncthreads();

  if (wave == 0) {
    float carry = 0.f;
    #pragma unroll
    for (int c = 0; c < 5; ++c) {
      const int idx = c * 64 + lane;
      float val = e[idx];
      #pragma unroll
      for (int off = 1; off < 64; off <<= 1) {
        const float nv = __shfl_up(val, off);
        if (lane >= off) val += nv;
      }
      const float incl = val + carry;       // S[idx+1]
      const int j = idx + 1;
      if (j < NC) Warr[j] = (j > i) ? 1.f / ((float)j * incl) : 0.f;
      carry += __shfl(val, 63);
    }
    if (lane == 0) Warr[0] = 0.f;

    carry = 0.f;
    #pragma unroll
    for (int c = 4; c >= 0; --c) {
      const int idx = c * 64 + lane;
      float val = Warr[idx];
      #pragma unroll
      for (int off = 1; off < 64; off <<= 1) {
        const float nv = __shfl_down(val, off);
        if (lane + off < 64) val += nv;
      }
      Csuf[idx] = val + carry;              // sum_{j>=idx} W[j]
      carry += __shfl(val, 0);
    }
    if (lane == 0) Csuf[NC] = 0.f;
  }
  __syncthreads();

  for (int kk = t; kk < NC; kk += 256) {
    const int mm = (i > kk) ? i : kk;
    atomicAdd(&P[kk], e[kk] * Csuf[mm + 1]);
  }
}

// ---------------------------------------------------------------------------
// out = sum_kk sum_e x[kk,e]*(P[kk]*h[e] + wx[e]) + (bv·wA)*(sum P) + NC*bc
// ---------------------------------------------------------------------------
__global__ __launch_bounds__(256) void finalize(
    const float* __restrict__ x, const float* __restrict__ P,
    const float* __restrict__ h, const float* __restrict__ Wc,
    const float* __restrict__ bc, const float* __restrict__ bv,
    float* __restrict__ out)
{
  const int kk   = blockIdx.x;
  const int t    = threadIdx.x;
  const int lane = t & 63;
  const int wave = t >> 6;

  __shared__ float tmp[4];
  __shared__ float tmp2[8];

  const float pk = P[kk];
  const float* xr = x + kk * DIM;
  float s = 0.f;
  for (int e = t; e < DIM; e += 256)
    s += xr[e] * fmaf(pk, h[e], Wc[DIM + e]);
  #pragma unroll
  for (int off = 32; off; off >>= 1) s += __shfl_down(s, off);
  if (lane == 0) tmp[wave] = s;

  if (kk == 0) {
    float ec = 0.f, ep = 0.f;
    for (int d = t; d < DIM; d += 256) ec += bv[d] * Wc[d];
    for (int mIdx = t; mIdx < NC; mIdx += 256) ep += P[mIdx];
    #pragma unroll
    for (int off = 32; off; off >>= 1) {
      ec += __shfl_down(ec, off);
      ep += __shfl_down(ep, off);
    }
    if (lane == 0) { tmp2[wave] = ec; tmp2[4 + wave] = ep; }
  }
  __syncthreads();

  if (t == 0) {
    float tot = tmp[0] + tmp[1] + tmp[2] + tmp[3];
    atomicAdd(out, tot);
    if (kk == 0) {
      const float c  = tmp2[0] + tmp2[1] + tmp2[2] + tmp2[3];
      const float sp = tmp2[4] + tmp2[5] + tmp2[6] + tmp2[7];
      atomicAdd(out, c * sp + (float)NC * bc[0]);
    }
  }
}

// ---------------------------------------------------------------------------
extern "C" void kernel_launch(void* const* d_in, const int* in_sizes, int n_in,
                              void* d_out, int out_size, void* d_ws, size_t ws_size,
                              hipStream_t stream) {
  const float* x  = (const float*)d_in[0];
  // d_in[1] = goal (unused by the reference forward)
  const float* Wq = (const float*)d_in[2];
  const float* bq = (const float*)d_in[3];
  const float* Wk = (const float*)d_in[4];
  const float* bk = (const float*)d_in[5];
  const float* Wv = (const float*)d_in[6];
  const float* bv = (const float*)d_in[7];
  const float* Wc = (const float*)d_in[8];
  const float* bc = (const float*)d_in[9];

  float* ws = (float*)d_ws;
  float* q  = ws;                       // 163840
  float* k  = ws + NC * DIM;            // 163840
  float* S  = ws + 2 * NC * DIM;        // 102400
  float* P  = S + NC * NC;              // 320
  float* h  = P + NC;                   // 512
  float* out = (float*)d_out;

  // q,k,S,P,h are all atomic accumulators -> zero the whole contiguous range
  hipMemsetAsync(ws, 0, (size_t)(2 * NC * DIM + NC * NC + NC + DIM) * sizeof(float), stream);
  hipMemsetAsync(out, 0, sizeof(float), stream);

  gemm_qk3<<<dim3(8, 5, 16), 256, 0, stream>>>(x, Wq, bq, Wk, bk, q, k);
  compute_h<<<dim3(2, 16), 256, 0, stream>>>(Wv, Wc, h);
  scores2<<<dim3(5, 5, 16), 256, 0, stream>>>(q, k, S);
  row_ops<<<NC, 256, 0, stream>>>(S, P);
  finalize<<<NC, 256, 0, stream>>>(x, P, h, Wc, bc, bv, out);
}

// Round 4
// 120.244 us; speedup vs baseline: 1.3132x; 1.3132x over previous
//
#include <hip/hip_runtime.h>

#define NC 320   // coalition size
#define DIM 512

// ---------------------------------------------------------------------------
// Split-K partials for q = x@Wq^T and k = x@Wk^T (bias added in reduce_qk).
// grid (8, 5, 16): x = col tile (64), y = row tile (64), z: mat=z>>3, split=z&7.
// 64x64 tile, BK=32, 4x4 micro-tile, K-chunk 64 per split.
// Direct float4 stores to private partial slice — NO atomics (R3 lesson:
// bulk global fp32 atomicAdd write-throughs to HBM and serializes, ~60/µs).
// ---------------------------------------------------------------------------
__global__ __launch_bounds__(256) void gemm_qk_part(
    const float* __restrict__ x,
    const float* __restrict__ Wq, const float* __restrict__ Wk,
    float* __restrict__ part)   // [2*8][NC][DIM]
{
  const int z = blockIdx.z;
  const float* __restrict__ W = (z & 8) ? Wk : Wq;
  const int kb = (z & 7) * 64;      // this split's K chunk [kb, kb+64)
  const int i0 = blockIdx.y * 64;
  const int c0 = blockIdx.x * 64;

  __shared__ __align__(16) float As[32][68];   // [kk][row]
  __shared__ __align__(16) float Bs[32][68];   // [kk][col]

  const int t  = threadIdx.x;
  const int sr = t >> 2;            // staged row/col 0..63
  const int kc = (t & 3) << 3;      // staged k offset 0,8,16,24
  const int ty = t >> 4;            // 0..15 row quad
  const int tx = t & 15;            // 0..15 col quad

  float acc[4][4] = {};

  const float* xp = x + (i0 + sr) * DIM + kc;
  const float* wp = W + (c0 + sr) * DIM + kc;

  for (int k0 = kb; k0 < kb + 64; k0 += 32) {
    const float4 xa = *(const float4*)(xp + k0);
    const float4 xb = *(const float4*)(xp + k0 + 4);
    const float4 wa = *(const float4*)(wp + k0);
    const float4 wb = *(const float4*)(wp + k0 + 4);
    __syncthreads();
    As[kc+0][sr]=xa.x; As[kc+1][sr]=xa.y; As[kc+2][sr]=xa.z; As[kc+3][sr]=xa.w;
    As[kc+4][sr]=xb.x; As[kc+5][sr]=xb.y; As[kc+6][sr]=xb.z; As[kc+7][sr]=xb.w;
    Bs[kc+0][sr]=wa.x; Bs[kc+1][sr]=wa.y; Bs[kc+2][sr]=wa.z; Bs[kc+3][sr]=wa.w;
    Bs[kc+4][sr]=wb.x; Bs[kc+5][sr]=wb.y; Bs[kc+6][sr]=wb.z; Bs[kc+7][sr]=wb.w;
    __syncthreads();
    #pragma unroll
    for (int kk = 0; kk < 32; ++kk) {
      const float4 a4 = *(const float4*)&As[kk][ty * 4];
      const float4 b4 = *(const float4*)&Bs[kk][tx * 4];
      const float a[4] = {a4.x, a4.y, a4.z, a4.w};
      const float b[4] = {b4.x, b4.y, b4.z, b4.w};
      #pragma unroll
      for (int i = 0; i < 4; ++i)
        #pragma unroll
        for (int j = 0; j < 4; ++j)
          acc[i][j] = fmaf(a[i], b[j], acc[i][j]);
    }
  }

  float* outp = part + (size_t)z * NC * DIM;
  #pragma unroll
  for (int i = 0; i < 4; ++i) {
    float4 o = {acc[i][0], acc[i][1], acc[i][2], acc[i][3]};
    *(float4*)&outp[(i0 + ty*4 + i) * DIM + c0 + tx*4] = o;
  }
}

// ---------------------------------------------------------------------------
// q/k = sum of 8 partials + bias. grid (160, 2): 160*256 float4 = 320*512.
// ---------------------------------------------------------------------------
__global__ __launch_bounds__(256) void reduce_qk(
    const float* __restrict__ part,
    const float* __restrict__ bq, const float* __restrict__ bk,
    float* __restrict__ q, float* __restrict__ k)
{
  const int mat = blockIdx.y;
  const int f   = blockIdx.x * 256 + threadIdx.x;   // float4 index
  const int row = f >> 7;          // 512/4 = 128 float4 per row
  const int col = (f & 127) * 4;
  const float* bias = mat ? bk : bq;
  float4 s = *(const float4*)&bias[col];
  const size_t off = (size_t)row * DIM + col;
  #pragma unroll
  for (int sp = 0; sp < 8; ++sp) {
    const float4 p = *(const float4*)&part[(size_t)(mat*8+sp) * NC * DIM + off];
    s.x += p.x; s.y += p.y; s.z += p.z; s.w += p.w;
  }
  float* out = mat ? k : q;
  *(float4*)&out[off] = s;
}

// ---------------------------------------------------------------------------
// Split-K partials for S = q·k^T. grid (5, 5, 8): kb = z*64.
// Same structure as gemm_qk_part. Scale folded into reduce_S.
// ---------------------------------------------------------------------------
__global__ __launch_bounds__(256) void scores_part(
    const float* __restrict__ q, const float* __restrict__ k,
    float* __restrict__ part)   // [8][NC][NC]
{
  const int z  = blockIdx.z;
  const int kb = z * 64;
  const int i0 = blockIdx.y * 64;
  const int j0 = blockIdx.x * 64;

  __shared__ __align__(16) float As[32][68];
  __shared__ __align__(16) float Bs[32][68];

  const int t  = threadIdx.x;
  const int sr = t >> 2;
  const int kc = (t & 3) << 3;
  const int ty = t >> 4;
  const int tx = t & 15;

  float acc[4][4] = {};

  const float* qp = q + (i0 + sr) * DIM + kc;
  const float* kp = k + (j0 + sr) * DIM + kc;

  for (int k0 = kb; k0 < kb + 64; k0 += 32) {
    const float4 qa = *(const float4*)(qp + k0);
    const float4 qb = *(const float4*)(qp + k0 + 4);
    const float4 ka = *(const float4*)(kp + k0);
    const float4 kb4= *(const float4*)(kp + k0 + 4);
    __syncthreads();
    As[kc+0][sr]=qa.x; As[kc+1][sr]=qa.y; As[kc+2][sr]=qa.z; As[kc+3][sr]=qa.w;
    As[kc+4][sr]=qb.x; As[kc+5][sr]=qb.y; As[kc+6][sr]=qb.z; As[kc+7][sr]=qb.w;
    Bs[kc+0][sr]=ka.x; Bs[kc+1][sr]=ka.y; Bs[kc+2][sr]=ka.z; Bs[kc+3][sr]=ka.w;
    Bs[kc+4][sr]=kb4.x;Bs[kc+5][sr]=kb4.y;Bs[kc+6][sr]=kb4.z;Bs[kc+7][sr]=kb4.w;
    __syncthreads();
    #pragma unroll
    for (int kk = 0; kk < 32; ++kk) {
      const float4 a4 = *(const float4*)&As[kk][ty * 4];
      const float4 b4 = *(const float4*)&Bs[kk][tx * 4];
      const float a[4] = {a4.x, a4.y, a4.z, a4.w};
      const float b[4] = {b4.x, b4.y, b4.z, b4.w};
      #pragma unroll
      for (int i = 0; i < 4; ++i)
        #pragma unroll
        for (int j = 0; j < 4; ++j)
          acc[i][j] = fmaf(a[i], b[j], acc[i][j]);
    }
  }

  float* outp = part + (size_t)z * NC * NC;
  #pragma unroll
  for (int i = 0; i < 4; ++i) {
    float4 o = {acc[i][0], acc[i][1], acc[i][2], acc[i][3]};
    *(float4*)&outp[(i0 + ty*4 + i) * NC + j0 + tx*4] = o;
  }
}

// ---------------------------------------------------------------------------
// S = scale * sum of 8 partials. grid (100): 100*256 float4 = 320*320.
// ---------------------------------------------------------------------------
__global__ __launch_bounds__(256) void reduce_S(
    const float* __restrict__ part, float* __restrict__ S)
{
  const int f = blockIdx.x * 256 + threadIdx.x;   // float4 index, < 25600
  const size_t off = (size_t)f * 4;
  float4 s = {0.f, 0.f, 0.f, 0.f};
  #pragma unroll
  for (int sp = 0; sp < 8; ++sp) {
    const float4 p = *(const float4*)&part[(size_t)sp * NC * NC + off];
    s.x += p.x; s.y += p.y; s.z += p.z; s.w += p.w;
  }
  const float scale = 0.044194173824159216f;  // 1/sqrt(512)
  s.x *= scale; s.y *= scale; s.z *= scale; s.w *= scale;
  *(float4*)&S[off] = s;
}

// ---------------------------------------------------------------------------
// h[e] = sum_d Wv[d,e] * wA[d]   (wA = Wc[0, 0:512])
// ---------------------------------------------------------------------------
__global__ __launch_bounds__(256) void compute_h(
    const float* __restrict__ Wv, const float* __restrict__ Wc,
    float* __restrict__ h)
{
  const int e  = blockIdx.x * 256 + threadIdx.x;  // 0..511
  const int d0 = blockIdx.y * 32;
  float s = 0.f;
  #pragma unroll
  for (int d = 0; d < 32; ++d)
    s = fmaf(Wv[(d0 + d) * DIM + e], Wc[d0 + d], s);
  atomicAdd(&h[e], s);
}

// ---------------------------------------------------------------------------
// One block per query row i, e[] read from precomputed S:
//   e = exp(S[i,:] - rowmax); prefix sums -> W[j]=1/(j*S[j]) for j>i;
//   Csuf[m] = sum_{j>=m} W[j];  P[kk] += e[kk]*Csuf[max(i,kk)+1]
// ---------------------------------------------------------------------------
__global__ __launch_bounds__(256) void row_ops(
    const float* __restrict__ S, float* __restrict__ P)
{
  const int i    = blockIdx.x;
  const int t    = threadIdx.x;
  const int lane = t & 63;
  const int wave = t >> 6;

  __shared__ float e[NC];
  __shared__ float Warr[NC];
  __shared__ float Csuf[NC + 1];
  __shared__ float wred[4];

  for (int kk = t; kk < NC; kk += 256) e[kk] = S[i * NC + kk];
  __syncthreads();

  float m = -1e30f;
  for (int kk = t; kk < NC; kk += 256) m = fmaxf(m, e[kk]);
  #pragma unroll
  for (int off = 32; off; off >>= 1) m = fmaxf(m, __shfl_down(m, off));
  if (lane == 0) wred[wave] = m;
  __syncthreads();
  m = fmaxf(fmaxf(wred[0], wred[1]), fmaxf(wred[2], wred[3]));

  for (int kk = t; kk < NC; kk += 256) e[kk] = __expf(e[kk] - m);
  __syncthreads();

  if (wave == 0) {
    float carry = 0.f;
    #pragma unroll
    for (int c = 0; c < 5; ++c) {
      const int idx = c * 64 + lane;
      float val = e[idx];
      #pragma unroll
      for (int off = 1; off < 64; off <<= 1) {
        const float nv = __shfl_up(val, off);
        if (lane >= off) val += nv;
      }
      const float incl = val + carry;       // S[idx+1]
      const int j = idx + 1;
      if (j < NC) Warr[j] = (j > i) ? 1.f / ((float)j * incl) : 0.f;
      carry += __shfl(val, 63);
    }
    if (lane == 0) Warr[0] = 0.f;

    carry = 0.f;
    #pragma unroll
    for (int c = 4; c >= 0; --c) {
      const int idx = c * 64 + lane;
      float val = Warr[idx];
      #pragma unroll
      for (int off = 1; off < 64; off <<= 1) {
        const float nv = __shfl_down(val, off);
        if (lane + off < 64) val += nv;
      }
      Csuf[idx] = val + carry;              // sum_{j>=idx} W[j]
      carry += __shfl(val, 0);
    }
    if (lane == 0) Csuf[NC] = 0.f;
  }
  __syncthreads();

  for (int kk = t; kk < NC; kk += 256) {
    const int mm = (i > kk) ? i : kk;
    atomicAdd(&P[kk], e[kk] * Csuf[mm + 1]);
  }
}

// ---------------------------------------------------------------------------
// out = sum_kk sum_e x[kk,e]*(P[kk]*h[e] + wx[e]) + (bv·wA)*(sum P) + NC*bc
// ---------------------------------------------------------------------------
__global__ __launch_bounds__(256) void finalize(
    const float* __restrict__ x, const float* __restrict__ P,
    const float* __restrict__ h, const float* __restrict__ Wc,
    const float* __restrict__ bc, const float* __restrict__ bv,
    float* __restrict__ out)
{
  const int kk   = blockIdx.x;
  const int t    = threadIdx.x;
  const int lane = t & 63;
  const int wave = t >> 6;

  __shared__ float tmp[4];
  __shared__ float tmp2[8];

  const float pk = P[kk];
  const float* xr = x + kk * DIM;
  float s = 0.f;
  for (int e = t; e < DIM; e += 256)
    s += xr[e] * fmaf(pk, h[e], Wc[DIM + e]);
  #pragma unroll
  for (int off = 32; off; off >>= 1) s += __shfl_down(s, off);
  if (lane == 0) tmp[wave] = s;

  if (kk == 0) {
    float ec = 0.f, ep = 0.f;
    for (int d = t; d < DIM; d += 256) ec += bv[d] * Wc[d];
    for (int mIdx = t; mIdx < NC; mIdx += 256) ep += P[mIdx];
    #pragma unroll
    for (int off = 32; off; off >>= 1) {
      ec += __shfl_down(ec, off);
      ep += __shfl_down(ep, off);
    }
    if (lane == 0) { tmp2[wave] = ec; tmp2[4 + wave] = ep; }
  }
  __syncthreads();

  if (t == 0) {
    float tot = tmp[0] + tmp[1] + tmp[2] + tmp[3];
    atomicAdd(out, tot);
    if (kk == 0) {
      const float c  = tmp2[0] + tmp2[1] + tmp2[2] + tmp2[3];
      const float sp = tmp2[4] + tmp2[5] + tmp2[6] + tmp2[7];
      atomicAdd(out, c * sp + (float)NC * bc[0]);
    }
  }
}

// ---------------------------------------------------------------------------
extern "C" void kernel_launch(void* const* d_in, const int* in_sizes, int n_in,
                              void* d_out, int out_size, void* d_ws, size_t ws_size,
                              hipStream_t stream) {
  const float* x  = (const float*)d_in[0];
  // d_in[1] = goal (unused by the reference forward)
  const float* Wq = (const float*)d_in[2];
  const float* bq = (const float*)d_in[3];
  const float* Wk = (const float*)d_in[4];
  const float* bk = (const float*)d_in[5];
  const float* Wv = (const float*)d_in[6];
  const float* bv = (const float*)d_in[7];
  const float* Wc = (const float*)d_in[8];
  const float* bc = (const float*)d_in[9];

  float* ws     = (float*)d_ws;
  float* q      = ws;                          // 163840
  float* k      = q + NC * DIM;                // 163840
  float* S      = k + NC * DIM;                // 102400
  float* P      = S + NC * NC;                 // 320
  float* h      = P + NC;                      // 512
  float* partQK = h + DIM;                     // 16 * 163840 = 2621440
  float* partS  = partQK + 16 * NC * DIM;      // 8 * 102400  = 819200
  float* out = (float*)d_out;

  // only the atomic accumulators need zeroing (P, h contiguous) + out
  hipMemsetAsync(P, 0, (NC + DIM) * sizeof(float), stream);
  hipMemsetAsync(out, 0, sizeof(float), stream);

  gemm_qk_part<<<dim3(8, 5, 16), 256, 0, stream>>>(x, Wq, Wk, partQK);
  reduce_qk<<<dim3(160, 2), 256, 0, stream>>>(partQK, bq, bk, q, k);
  compute_h<<<dim3(2, 16), 256, 0, stream>>>(Wv, Wc, h);
  scores_part<<<dim3(5, 5, 8), 256, 0, stream>>>(q, k, partS);
  reduce_S<<<100, 256, 0, stream>>>(partS, S);
  row_ops<<<NC, 256, 0, stream>>>(S, P);
  finalize<<<NC, 256, 0, stream>>>(x, P, h, Wc, bc, bv, out);
}